// Round 11
// baseline (3283.476 us; speedup 1.0000x reference)
//
#include <hip/hip_runtime.h>

// ============================================================================
// Siamese 3-layer masked LSTM (B=32, 2 sides, T=1024, F=128, H=256)
// Round 11: OPERAND-SWAPPED MFMA (z^T) + 4B tag-in-data + XCD fast path.
//   - D = A*B with A := weight frags, B := [x|h] frags (fragments identical to
//     before; only arg order changes). acc[nt][r] = gate r of hid w*16+nt*4+lk,
//     seq = l15  ->  NO z transpose LDS (round-10's 8-way-conflict hotspot),
//     gates read acc directly, publish is 4 coalesced dword stores.
//   - Exchange words are 4B [bf16 | tag16] (tag = t+1 <= 1024), single dword
//     store = atomic pairing. Tile per (t, group) = [hid 0..255][seq 0..15]
//     word = hid*16+seq (16KB). Consumers: 2 waves poll h halves, 2 poll x
//     halves, de-tag into LDS [seq][264-short rows]; all waves frag-read.
//   - Deferred inter-layer publish issued right AFTER the comms barrier and
//     drained by vmcnt(0) AFTER the MFMA block (ack hides under compute), so
//     the next poll's vmcnt(0) (in-order retirement!) no longer eats sc1 acks.
//   - XCD probe/consensus fast path (round 10) kept: sibling ring via plain
//     stores + sc0 polls when colocated, sc1 fallback always-correct.
// ============================================================================

typedef __attribute__((ext_vector_type(8))) short bf16x8;
typedef __attribute__((ext_vector_type(4))) float f32x4;
typedef __attribute__((ext_vector_type(4))) unsigned int u32x4;
typedef unsigned long long ull;

__device__ __forceinline__ unsigned short f2bf(float f){
    unsigned u = __float_as_uint(f);
    u += 0x7FFFu + ((u >> 16) & 1u);        // round-to-nearest-even
    return (unsigned short)(u >> 16);
}
__device__ __forceinline__ float fsig(float x){
    return __builtin_amdgcn_rcpf(1.0f + __expf(-x));
}
__device__ __forceinline__ float ftanh(float x){
    float e = __expf(-2.0f * fabsf(x));
    return copysignf((1.0f - e) * __builtin_amdgcn_rcpf(1.0f + e), x);
}
__device__ __forceinline__ ull ald(const ull* p){
    return __hip_atomic_load(p, __ATOMIC_RELAXED, __HIP_MEMORY_SCOPE_AGENT);
}
__device__ __forceinline__ void ast(unsigned int* p, unsigned int v){
    __hip_atomic_store(p, v, __ATOMIC_RELAXED, __HIP_MEMORY_SCOPE_AGENT);
}
__device__ __forceinline__ void st_pair(ull* p, ull v){
    asm volatile("global_store_dwordx2 %0, %1, off sc1" :: "v"((ull)p), "v"(v) : "memory");
}
__device__ __forceinline__ void st_plain8(ull* p, ull v){
    asm volatile("global_store_dwordx2 %0, %1, off" :: "v"((ull)p), "v"(v) : "memory");
}
__device__ __forceinline__ void stw_sc1(unsigned* p, unsigned v){
    asm volatile("global_store_dword %0, %1, off sc1" :: "v"((ull)p), "v"(v) : "memory");
}
__device__ __forceinline__ void stw_plain(unsigned* p, unsigned v){
    asm volatile("global_store_dword %0, %1, off" :: "v"((ull)p), "v"(v) : "memory");
}
__device__ __forceinline__ int min16(const ull* p){
    int m = 0x7FFFFFFF;
    #pragma unroll
    for (int i = 0; i < 8; ++i){
        ull v = ald(p + i);
        m = min(m, min((int)(unsigned)v, (int)(v >> 32)));
    }
    return m;
}

// 4 coalesced dwordx4, 1KB stride (tagged tile rows)
#define POLL4_SC1(P, Q0,Q1,Q2,Q3)                                        \
  asm volatile("global_load_dwordx4 %0, %4, off sc1\n\t"                 \
               "global_load_dwordx4 %1, %4, off offset:1024 sc1\n\t"     \
               "global_load_dwordx4 %2, %4, off offset:2048 sc1\n\t"     \
               "global_load_dwordx4 %3, %4, off offset:3072 sc1"         \
               : "=&v"(Q0),"=&v"(Q1),"=&v"(Q2),"=&v"(Q3)                 \
               : "v"(P) : "memory")
#define POLL4_SC0(P, Q0,Q1,Q2,Q3)                                        \
  asm volatile("global_load_dwordx4 %0, %4, off sc0\n\t"                 \
               "global_load_dwordx4 %1, %4, off offset:1024 sc0\n\t"     \
               "global_load_dwordx4 %2, %4, off offset:2048 sc0\n\t"     \
               "global_load_dwordx4 %3, %4, off offset:3072 sc0"         \
               : "=&v"(Q0),"=&v"(Q1),"=&v"(Q2),"=&v"(Q3)                 \
               : "v"(P) : "memory")
// untagged L0 x loads
#define PLAIN4(P, O0,O1,O2,O3)                                           \
  asm volatile("global_load_dwordx4 %0, %4, off\n\t"                     \
               "global_load_dwordx4 %1, %4, off offset:1024\n\t"         \
               "global_load_dwordx4 %2, %4, off offset:2048\n\t"         \
               "global_load_dwordx4 %3, %4, off offset:3072"             \
               : "=&v"(O0),"=&v"(O1),"=&v"(O2),"=&v"(O3)                 \
               : "v"(P) : "memory")

__device__ __forceinline__ bool tagsok(u32x4 q, unsigned tg){
    return ((q.x >> 16) == tg) && ((q.y >> 16) == tg) &&
           ((q.z >> 16) == tg) && ((q.w >> 16) == tg);
}

// poll one half (hids half*128..+128, 8KB) of a tagged tile; de-tag into LDS
template<bool FAST>
__device__ __forceinline__ void poll_tile(const char* tile, unsigned tg, int half,
                                          unsigned short (*buf)[264], int lane){
    const ull b0 = (ull)(tile + half * 8192 + lane * 16);
    u32x4 q0,q1,q2,q3,q4,q5,q6,q7;
    int spins = 0;
    for (;;){
        if (FAST){
            POLL4_SC0(b0,        q0, q1, q2, q3);
            POLL4_SC0(b0 + 4096, q4, q5, q6, q7);
        } else {
            POLL4_SC1(b0,        q0, q1, q2, q3);
            POLL4_SC1(b0 + 4096, q4, q5, q6, q7);
        }
        asm volatile("s_waitcnt vmcnt(0)" ::: "memory");
        __builtin_amdgcn_sched_barrier(0);
        bool ok = tagsok(q0, tg) & tagsok(q1, tg) & tagsok(q2, tg) & tagsok(q3, tg)
                & tagsok(q4, tg) & tagsok(q5, tg) & tagsok(q6, tg) & tagsok(q7, tg);
        if (__all(ok)) break;
        if (((++spins) & 15) == 0) __builtin_amdgcn_s_sleep(1);
    }
    // quad it covers hid = half*128 + it*16 + (lane>>2), seqs (lane&3)*4 .. +3
    const int hb = half * 128 + (lane >> 2);
    const int sb = (lane & 3) * 4;
#define DETAG(Q, IT) { int hh = hb + (IT)*16;                     \
    buf[sb+0][hh] = (unsigned short)(Q).x;                        \
    buf[sb+1][hh] = (unsigned short)(Q).y;                        \
    buf[sb+2][hh] = (unsigned short)(Q).z;                        \
    buf[sb+3][hh] = (unsigned short)(Q).w; }
    DETAG(q0,0) DETAG(q1,1) DETAG(q2,2) DETAG(q3,3)
    DETAG(q4,4) DETAG(q5,5) DETAG(q6,6) DETAG(q7,7)
#undef DETAG
}

// bounded end-to-end probe of the fast path (plain store -> sc0 load)
__device__ __forceinline__ bool probe_quad(ull* pb, ull nonce, int n){
    st_plain8(pb + n, nonce);
    for (int it = 0; it < 400; ++it){
        ull a0, a1, a2, a3;
        asm volatile("global_load_dwordx2 %0, %4, off sc0\n\t"
                     "global_load_dwordx2 %1, %4, off offset:8 sc0\n\t"
                     "global_load_dwordx2 %2, %4, off offset:16 sc0\n\t"
                     "global_load_dwordx2 %3, %4, off offset:24 sc0\n\t"
                     "s_waitcnt vmcnt(0)"
                     : "=&v"(a0),"=&v"(a1),"=&v"(a2),"=&v"(a3)
                     : "v"((ull)pb) : "memory");
        if (a0 == nonce && a1 == nonce && a2 == nonce && a3 == nonce) return true;
        __builtin_amdgcn_s_sleep(2);
    }
    return false;
}
__device__ __forceinline__ bool consensus(ull* vd, ull nonce, int n, bool seen){
    st_pair(vd + n, (nonce << 1) | (seen ? 1ull : 0ull));
    for (;;){
        ull a0, a1, a2, a3;
        asm volatile("global_load_dwordx2 %0, %4, off sc1\n\t"
                     "global_load_dwordx2 %1, %4, off offset:8 sc1\n\t"
                     "global_load_dwordx2 %2, %4, off offset:16 sc1\n\t"
                     "global_load_dwordx2 %3, %4, off offset:24 sc1\n\t"
                     "s_waitcnt vmcnt(0)"
                     : "=&v"(a0),"=&v"(a1),"=&v"(a2),"=&v"(a3)
                     : "v"((ull)vd) : "memory");
        if ((a0 >> 1) == nonce && (a1 >> 1) == nonce &&
            (a2 >> 1) == nonce && (a3 >> 1) == nonce)
            return (a0 & a1 & a2 & a3 & 1ull) != 0;
        __builtin_amdgcn_s_sleep(1);
    }
}

// ---------------------------------------------------------------------------
// prep: bf16 cast into fragment-major xb + bit-packed mask + epoch bump
// ---------------------------------------------------------------------------
__global__ void prep_kernel(const float* __restrict__ x, unsigned int* __restrict__ xb,
                            unsigned int* __restrict__ mb, unsigned* __restrict__ epoch){
    const int s = blockIdx.x, c = blockIdx.y, l = threadIdx.x;
    if (s == 0 && c == 0 && l == 0) atomicAdd(epoch, 1u);
    const int g = s >> 4, sg = s & 15;
    const int woff = ((l >> 4) * 4 + ((l >> 2) & 3)) * 64 + sg * 4 + (l & 3);
    const float* xs = x + ((size_t)s * 1024 + (size_t)c * 64) * 128;
    unsigned int w0 = 0, w1 = 0;
    for (int tt = 0; tt < 64; ++tt){
        const float2 v = *(const float2*)(xs + (size_t)tt * 128 + 2 * l);
        bool nz = (v.x != 0.0f) || (v.y != 0.0f);
        unsigned long long b = __ballot(nz);
        if (b){ if (tt < 32) w0 |= 1u << tt; else w1 |= 1u << (tt - 32); }
        unsigned int p = (unsigned)f2bf(v.x) | ((unsigned)f2bf(v.y) << 16);
        xb[((size_t)(c * 64 + tt) * 4 + g) * 1024 + woff] = p;
    }
    if (l == 0){ mb[s * 32 + c * 2] = w0; mb[s * 32 + c * 2 + 1] = w1; }
}

// ---------------------------------------------------------------------------
template<int LAYER>
__device__ __forceinline__ void scan_layer(
    int g, int n,
    const unsigned int* __restrict__ xb0,     // L0 input (untagged, frag-major)
    const unsigned int* xin,                  // inter-layer input ring (tagged 4B)
    unsigned int* sring,                      // sibling ring (8-deep, tagged 4B)
    unsigned int* xout,                       // inter-layer output ring (LAYER<2)
    const float* __restrict__ W, const float* __restrict__ U, const float* __restrict__ Bv,
    const unsigned int* __restrict__ mb,
    float* __restrict__ hfinal,               // layer2 only
    int* prog, ull* probe, ull* verd, unsigned ep)
{
    constexpr int DK = (LAYER == 0) ? 4 : 8;
    constexpr int KT = DK + 8;
    const int lg = LAYER * 4 + g;
    const int tid  = threadIdx.x;
    const int w    = tid >> 6;
    const int lane = tid & 63;
    const int l15  = lane & 15, lk = lane >> 4;

    __shared__ unsigned short hT[2][16][264];   // [seq][hid] bf16, 528B rows
    __shared__ unsigned short xT[2][16][264];
    __shared__ unsigned int mbL[16][32];
    __shared__ int sgl, sFast;
    if (tid == 0) sgl = 0;
    for (int i = tid; i < 512; i += 256)
        mbL[i >> 5][i & 31] = mb[(g * 16 + (i >> 5)) * 32 + (i & 31)];
    __syncthreads();
    if (tid < 16){
        int last = 0;
        #pragma unroll
        for (int q = 0; q < 32; ++q){
            unsigned v = mbL[tid][q];
            if (v) last = q * 32 + (32 - __clz(v));
        }
        atomicMax(&sgl, last);
    }

    // ---- register-resident weight fragments (A operand) + per-gate bias -----
    // A rows for acc[nt] = gate cols w*64+nt*16+0..15; lane l15 -> row l15.
    int gcol[4];
    #pragma unroll
    for (int nt = 0; nt < 4; ++nt){
        int lc = w * 64 + nt * 16 + l15;
        gcol[nt] = (lc & 3) * 256 + n * 64 + (lc >> 2);
    }
    float bfr2[4][4];
    #pragma unroll
    for (int nt = 0; nt < 4; ++nt)
        #pragma unroll
        for (int r = 0; r < 4; ++r)
            bfr2[nt][r] = Bv[r * 256 + n * 64 + w * 16 + nt * 4 + lk];
    bf16x8 Bf[KT][4];
    #pragma unroll
    for (int kt = 0; kt < KT; ++kt){
        const float* src = (kt < DK) ? (W + (size_t)(kt * 32 + lk * 8) * 1024)
                                     : (U + (size_t)((kt - DK) * 32 + lk * 8) * 1024);
        #pragma unroll
        for (int nt = 0; nt < 4; ++nt){
            bf16x8 v;
            #pragma unroll
            for (int j = 0; j < 8; ++j) v[j] = (short)f2bf(src[(size_t)j * 1024 + gcol[nt]]);
            Bf[kt][nt] = v;
        }
    }
    // ---- colocation probe + consensus (tid 0) ------------------------------
    if (tid == 0){
        ull nonce = (((ull)ep) << 8) | 0xA5u;
        bool seen = probe_quad(probe + (size_t)lg * 8, nonce, n);
        sFast = consensus(verd + (size_t)lg * 8, nonce, n, seen) ? 1 : 0;
    }
    __syncthreads();
    const int gl = sgl;
    const bool fast = (sFast != 0);

    const int hhalf = (w == 0) ? 0 : (w == 2) ? 1 : -1;
    const int xhalf = (w == 1) ? 0 : (w == 3) ? 1 : -1;

    float cs[4] = {0, 0, 0, 0}, hs[4] = {0, 0, 0, 0};
    // publish base: word = (n*64 + w*16 + nt*4)*16 + lane  (coalesced per nt)
    const int pubbase = (n * 64 + w * 16) * 16 + lane;
    unsigned xv[4]; int tprev = -1;           // deferred inter-layer publish

    for (int t = 0; t < gl; ++t){
        // ---- progress publish / producer overwrite gate (amortized) ----------
        if (LAYER > 0 && (t & 31) == 0 && lane == 0)
            ast((unsigned*)(prog + (LAYER - 1) * 64 + g * 16 + n * 4 + w), (unsigned)t);
        if (LAYER < 2 && (t & 31) == 0){
            const ull* pp = (const ull*)(prog + LAYER * 64 + g * 16);
            int spins = 0;
            while (min16(pp) < t - 96)
                if (((++spins) & 15) == 0) __builtin_amdgcn_s_sleep(1);
        }

        // ---- L0 x: untagged B-frag loads, issued before the poll --------------
        u32x4 xq0, xq1, xq2, xq3;
        if (LAYER == 0){
            ull xaddr = (ull)((const char*)(xb0 + ((size_t)t * 4 + g) * 1024) + lane * 16);
            PLAIN4(xaddr, xq0, xq1, xq2, xq3);
        }
        // ---- comms: de-tag fresh tiles into LDS -------------------------------
        const int p = t & 1;
        if (t > 0 && hhalf >= 0){
            const char* tile = (const char*)sring + (((size_t)((t - 1) & 7) * 4 + g) * 16384);
            if (fast) poll_tile<true >(tile, (unsigned)t, hhalf, hT[p], lane);
            else      poll_tile<false>(tile, (unsigned)t, hhalf, hT[p], lane);
        }
        if (LAYER > 0 && xhalf >= 0)
            poll_tile<false>((const char*)xin + (((size_t)(t & 127) * 4 + g) * 16384),
                             (unsigned)(t + 1), xhalf, xT[p], lane);
        __syncthreads();
        if (LAYER == 0){   // rule #18: fence asm-load outputs before register use
            asm volatile("s_waitcnt vmcnt(0)" ::: "memory");
            __builtin_amdgcn_sched_barrier(0);
        }

        // ---- deferred inter-layer publish: issue early, drain after MFMA ------
        if (LAYER < 2 && tprev >= 0){
            unsigned* xd = xout + ((size_t)(tprev & 127) * 4 + g) * 4096 + pubbase;
            #pragma unroll
            for (int nt = 0; nt < 4; ++nt) stw_sc1(xd + nt * 64, xv[nt]);
            __builtin_amdgcn_sched_barrier(0);   // pin stores before compute
        }

        // ---- MFMA: z^T = bias + W^T x + U^T h  (A = weights, B = x/h) ---------
        f32x4 acc[4];
        #pragma unroll
        for (int nt = 0; nt < 4; ++nt)
            acc[nt] = (f32x4){bfr2[nt][0], bfr2[nt][1], bfr2[nt][2], bfr2[nt][3]};
        if (LAYER == 0){
            bf16x8 b0 = __builtin_bit_cast(bf16x8, xq0);
            bf16x8 b1 = __builtin_bit_cast(bf16x8, xq1);
            bf16x8 b2 = __builtin_bit_cast(bf16x8, xq2);
            bf16x8 b3 = __builtin_bit_cast(bf16x8, xq3);
            #pragma unroll
            for (int nt = 0; nt < 4; ++nt){
                acc[nt] = __builtin_amdgcn_mfma_f32_16x16x32_bf16(Bf[0][nt], b0, acc[nt], 0, 0, 0);
                acc[nt] = __builtin_amdgcn_mfma_f32_16x16x32_bf16(Bf[1][nt], b1, acc[nt], 0, 0, 0);
                acc[nt] = __builtin_amdgcn_mfma_f32_16x16x32_bf16(Bf[2][nt], b2, acc[nt], 0, 0, 0);
                acc[nt] = __builtin_amdgcn_mfma_f32_16x16x32_bf16(Bf[3][nt], b3, acc[nt], 0, 0, 0);
            }
        } else {
            #pragma unroll
            for (int kt = 0; kt < 8; ++kt){
                bf16x8 b = *(const bf16x8*)(&xT[p][l15][kt * 32 + lk * 8]);
                #pragma unroll
                for (int nt = 0; nt < 4; ++nt)
                    acc[nt] = __builtin_amdgcn_mfma_f32_16x16x32_bf16(Bf[kt][nt], b, acc[nt], 0, 0, 0);
            }
        }
        if (t > 0){
            #pragma unroll
            for (int kk = 0; kk < 8; ++kk){
                bf16x8 b = *(const bf16x8*)(&hT[p][l15][kk * 32 + lk * 8]);
                #pragma unroll
                for (int nt = 0; nt < 4; ++nt)
                    acc[nt] = __builtin_amdgcn_mfma_f32_16x16x32_bf16(Bf[DK + kk][nt], b, acc[nt], 0, 0, 0);
            }
        }
        asm volatile("s_waitcnt vmcnt(0)" ::: "memory");   // drain deferred acks

        // ---- gates: acc[nt][r] = gate r of hid w*16+nt*4+lk, seq l15 ----------
        bool m = (mbL[l15][t >> 5] >> (t & 31)) & 1;
        #pragma unroll
        for (int nt = 0; nt < 4; ++nt){
            float i_ = acc[nt][0], f_ = acc[nt][1], g_ = acc[nt][2], o_ = acc[nt][3];
            float cn = fsig(f_) * cs[nt] + fsig(i_) * ftanh(g_);
            float hn = fsig(o_) * ftanh(cn);
            if (m){ cs[nt] = cn; hs[nt] = hn; }
        }

        // ---- publish h(t): 4 coalesced tagged dwords; sibling now, x deferred -
        unsigned tg = ((unsigned)(t + 1)) << 16;
        unsigned v0 = (unsigned)f2bf(hs[0]) | tg, v1 = (unsigned)f2bf(hs[1]) | tg;
        unsigned v2 = (unsigned)f2bf(hs[2]) | tg, v3 = (unsigned)f2bf(hs[3]) | tg;
        unsigned* sd = sring + ((size_t)(t & 7) * 4 + g) * 4096 + pubbase;
        if (fast){
            stw_plain(sd, v0); stw_plain(sd + 64, v1);
            stw_plain(sd + 128, v2); stw_plain(sd + 192, v3);
        } else {
            stw_sc1(sd, v0); stw_sc1(sd + 64, v1);
            stw_sc1(sd + 128, v2); stw_sc1(sd + 192, v3);
        }
        if (LAYER < 2){ xv[0] = v0; xv[1] = v1; xv[2] = v2; xv[3] = v3; tprev = t; }
    }

    // epilogue: flush last deferred inter-layer publish + release producers
    if (LAYER < 2 && tprev >= 0){
        unsigned* xd = xout + ((size_t)(tprev & 127) * 4 + g) * 4096 + pubbase;
        #pragma unroll
        for (int nt = 0; nt < 4; ++nt) stw_sc1(xd + nt * 64, xv[nt]);
    }
    if (LAYER > 0 && lane == 0)
        ast((unsigned*)(prog + (LAYER - 1) * 64 + g * 16 + n * 4 + w), 0x40000000u);

    if (LAYER == 2){
        const int seqg = g * 16 + l15;
        #pragma unroll
        for (int nt = 0; nt < 4; ++nt)
            hfinal[(size_t)seqg * 256 + n * 64 + w * 16 + nt * 4 + lk] = hs[nt];
    }
}

__global__ __launch_bounds__(256, 1) void scan3_kernel(
    const unsigned int* xb, unsigned int* x01, unsigned int* x12,
    unsigned int* s0, unsigned int* s1, unsigned int* s2,
    const float* W0, const float* U0, const float* b0,
    const float* W1, const float* U1, const float* b1,
    const float* W2, const float* U2, const float* b2,
    const unsigned int* mb, int* prog, unsigned* epoch,
    ull* probe, ull* verd, float* hfinal)
{
    // quad q -> member bids { (q%8) + 8*(4*(q/8)+n) }: all == q (mod 8) -> one XCD
    const int xcd = blockIdx.x & 7, slot = blockIdx.x >> 3;
    const int q = xcd + 8 * (slot >> 2);
    if (q >= 12) return;
    const int n = slot & 3;
    const int layer = q >> 2, g = q & 3;
    const unsigned ep = *epoch;
    if (layer == 0)
        scan_layer<0>(g, n, xb, nullptr, s0, x01, W0, U0, b0, mb, nullptr, prog, probe, verd, ep);
    else if (layer == 1)
        scan_layer<1>(g, n, nullptr, x01, s1, x12, W1, U1, b1, mb, nullptr, prog, probe, verd, ep);
    else
        scan_layer<2>(g, n, nullptr, x12, s2, nullptr, W2, U2, b2, mb, hfinal, prog, probe, verd, ep);
}

// ---------------------------------------------------------------------------
__global__ void final_kernel(const float* __restrict__ hfinal, const float* __restrict__ dw,
                             const float* __restrict__ db, float* __restrict__ out){
    const int b = threadIdx.x >> 3, j = threadIdx.x & 7;
    const float* ha = hfinal + (size_t)(2 * b) * 256;
    const float* hb = ha + 256;
    float s = 0.0f;
    for (int d = j; d < 256; d += 8){ float df = ha[d] - hb[d]; s += df * df; }
    #pragma unroll
    for (int off = 4; off; off >>= 1) s += __shfl_xor(s, off, 8);
    if (j == 0){
        float dist = sqrtf(s);
        dist = fminf(fmaxf(dist, 1e-7f), 1e7f);
        out[b] = 1.0f / (1.0f + __expf(-(dist * dw[0] + db[0])));
    }
}

// ---------------------------------------------------------------------------
extern "C" void kernel_launch(void* const* d_in, const int* in_sizes, int n_in,
                              void* d_out, int out_size, void* d_ws, size_t ws_size,
                              hipStream_t stream){
    const float* x  = (const float*)d_in[0];
    const float* W0 = (const float*)d_in[1];
    const float* U0 = (const float*)d_in[2];
    const float* b0 = (const float*)d_in[3];
    const float* W1 = (const float*)d_in[4];
    const float* U1 = (const float*)d_in[5];
    const float* b1 = (const float*)d_in[6];
    const float* W2 = (const float*)d_in[7];
    const float* U2 = (const float*)d_in[8];
    const float* b2 = (const float*)d_in[9];
    const float* dw = (const float*)d_in[10];
    const float* db = (const float*)d_in[11];

    // workspace (~35.2 MB). Tagged rings replay-safe WITHOUT memset (tag match
    // + deterministic values; first launch sees 0xAAAA tags > 1025 -> rejected).
    char* ws = (char*)d_ws;
    unsigned int* xb     = (unsigned int*)(ws);                    // 16 MB
    unsigned int* x01    = (unsigned int*)(ws + 16777216ull);      // 8 MB (L0->L1)
    unsigned int* x12    = (unsigned int*)(ws + 25165824ull);      // 8 MB (L1->L2)
    unsigned int* s0     = (unsigned int*)(ws + 33554432ull);      // 512 KB sibling
    unsigned int* s1     = (unsigned int*)(ws + 34078720ull);      // 512 KB
    unsigned int* s2     = (unsigned int*)(ws + 34603008ull);      // 512 KB
    int*          prog   = (int*)(ws + 35127296ull);               // 512 B (memset)
    unsigned*     epoch  = (unsigned*)(ws + 35127808ull);          // persistent
    ull*          probe  = (ull*)(ws + 35128320ull);               // 768 B
    ull*          verd   = (ull*)(ws + 35129088ull);               // 768 B
    unsigned int* mb     = (unsigned int*)(ws + 35131392ull);      // 8 KB
    float*        hfinal = (float*)(ws + 35139584ull);             // 64 KB
    float*        out    = (float*)d_out;

    (void)hipMemsetAsync(ws + 35127296ull, 0, 512, stream);        // prog only

    prep_kernel<<<dim3(64, 16), 64, 0, stream>>>(x, xb, mb, epoch);
    scan3_kernel<<<64, 256, 0, stream>>>(xb, x01, x12, s0, s1, s2,
                                         W0, U0, b0, W1, U1, b1, W2, U2, b2,
                                         mb, prog, epoch, probe, verd, hfinal);
    final_kernel<<<1, 256, 0, stream>>>(hfinal, dw, db, out);
}